// Round 3
// baseline (135.665 us; speedup 1.0000x reference)
//
#include <hip/hip_runtime.h>
#include <math.h>

// Shapes: pred_logits [16,900,151] f32, pred_boxes [16,900,4] f32,
//         tgt_labels [16,100] i32, tgt_boxes [16,100,4] f32
//         out C [14400,1600] f32
#define NROWS 14400
#define NT    1600
#define NC    151
#define RPB   32            // rows per block in cost kernel

// ws layout: rowdata [14400*12 f32] at 0 (691200 B), prob [14400*151 f32] after.
#define ROWDATA_BYTES (NROWS * 12 * 4)
#define PROB_BYTES    ((size_t)NROWS * NC * 4)
#define WS_NEEDED     (ROWDATA_BYTES + PROB_BYTES)   // 9,388,800 B

// ---------------------------------------------------------------------------
// Kernel 1: one wave per query row. Softmax over 151 classes; writes the full
// prob row (coalesced) + 12-float row descriptor:
//   [0..3] cx,cy,w,h  [4..7] x0,y0,x1,y1  [8] area  [9] rmax [10] rinv
// ---------------------------------------------------------------------------
__global__ __launch_bounds__(256) void row_prep(
    const float* __restrict__ logits,
    const float* __restrict__ pboxes,
    float* __restrict__ rowdata,
    float* __restrict__ prob)          // may be null (fallback mode)
{
    const int wave = threadIdx.x >> 6;
    const int lane = threadIdx.x & 63;
    const int r = blockIdx.x * 4 + wave;           // 3600*4 = 14400 exact

    const float* row = logits + (size_t)r * NC;
    float v0 = row[lane];
    float v1 = row[lane + 64];
    float v2 = (lane < NC - 128) ? row[lane + 128] : -3.4e38f;

    float m = fmaxf(fmaxf(v0, v1), v2);
    #pragma unroll
    for (int off = 32; off; off >>= 1) m = fmaxf(m, __shfl_xor(m, off, 64));

    float e0 = __expf(v0 - m), e1 = __expf(v1 - m);
    float e2 = (lane < NC - 128) ? __expf(v2 - m) : 0.0f;
    float s = e0 + e1 + e2;
    #pragma unroll
    for (int off = 32; off; off >>= 1) s += __shfl_xor(s, off, 64);
    const float rinv = 1.0f / s;                   // uniform across wave

    if (prob) {
        float* pr = prob + (size_t)r * NC;
        pr[lane]      = e0 * rinv;
        pr[lane + 64] = e1 * rinv;
        if (lane < NC - 128) pr[lane + 128] = e2 * rinv;
    }

    if (lane == 0) {
        float4 pb = ((const float4*)pboxes)[r];
        float x0 = pb.x - 0.5f * pb.z, y0 = pb.y - 0.5f * pb.w;
        float x1 = pb.x + 0.5f * pb.z, y1 = pb.y + 0.5f * pb.w;
        float area = (x1 - x0) * (y1 - y0);
        float* o = rowdata + (size_t)r * 12;
        ((float4*)o)[0] = make_float4(pb.x, pb.y, pb.z, pb.w);
        ((float4*)o)[1] = make_float4(x0, y0, x1, y1);
        ((float4*)o)[2] = make_float4(area, m, rinv, 0.0f);
    }
}

// ---------------------------------------------------------------------------
// Kernel 2 (main): lanes = targets (coalesced stores). Each block stages its
// 32 rows' prob slice (contiguous in global) and row descriptors into LDS,
// then the inner loop gathers the class prob from LDS instead of global.
// grid (5, 450), block 320 -> t covered exactly, no tail.
// ---------------------------------------------------------------------------
__global__ __launch_bounds__(320) void cost_kernel(
    const int*   __restrict__ tlabels,
    const float* __restrict__ tboxes,
    const float* __restrict__ rowdata,
    const float* __restrict__ prob,
    float* __restrict__ out)
{
    __shared__ float sprob[RPB * NC];   // 4832 f32 = 19328 B
    __shared__ float srow[RPB * 12];    // 384 f32

    const int tid = threadIdx.x;
    const int r0 = blockIdx.y * RPB;

    // stage prob rows: global span [r0*151, r0*151+4832) is contiguous
    const float* gp = prob + (size_t)r0 * NC;
    for (int i = tid; i < RPB * NC; i += 320) sprob[i] = gp[i];
    // BUGFIX R2: RPB*12 = 384 > 320 threads -> must be a strided loop,
    // otherwise srow[320..383] (rows 26-31) is uninitialized LDS garbage.
    const float* gr = rowdata + (size_t)r0 * 12;
    for (int i = tid; i < RPB * 12; i += 320) srow[i] = gr[i];

    const int t = blockIdx.x * 320 + tid;           // < 1600 always
    const float4 tb = ((const float4*)tboxes)[t];
    const int label = tlabels[t];
    const float tx0 = tb.x - 0.5f * tb.z, ty0 = tb.y - 0.5f * tb.w;
    const float tx1 = tb.x + 0.5f * tb.z, ty1 = tb.y + 0.5f * tb.w;
    const float tarea = (tx1 - tx0) * (ty1 - ty0);

    __syncthreads();

    size_t oaddr = (size_t)r0 * NT + t;
    #pragma unroll 4
    for (int i = 0; i < RPB; ++i) {
        const float4* rd = (const float4*)(srow + i * 12);
        const float4 pb  = rd[0];
        const float4 pxy = rd[1];
        const float  parea = rd[2].x;

        const float cls = sprob[i * NC + label];    // LDS gather

        const float l1 = fabsf(pb.x - tb.x) + fabsf(pb.y - tb.y) +
                         fabsf(pb.z - tb.z) + fabsf(pb.w - tb.w);

        const float iw = fmaxf(fminf(pxy.z, tx1) - fmaxf(pxy.x, tx0), 0.0f);
        const float ih = fmaxf(fminf(pxy.w, ty1) - fmaxf(pxy.y, ty0), 0.0f);
        const float inter = iw * ih;
        const float uni   = parea + tarea - inter;
        const float iou   = inter * __builtin_amdgcn_rcpf(uni);
        const float ew = fmaxf(pxy.z, tx1) - fminf(pxy.x, tx0);
        const float eh = fmaxf(pxy.w, ty1) - fminf(pxy.y, ty0);
        const float earea = ew * eh;
        const float giou  = iou - (earea - uni) * __builtin_amdgcn_rcpf(earea);

        out[oaddr] = 5.0f * l1 - cls - 2.0f * giou;
        oaddr += NT;
    }
}

// ---------------------------------------------------------------------------
// Fallback main kernel (R1 structure, global gather) if ws too small.
// ---------------------------------------------------------------------------
__global__ __launch_bounds__(320) void cost_kernel_fb(
    const float* __restrict__ logits,
    const int*   __restrict__ tlabels,
    const float* __restrict__ tboxes,
    const float* __restrict__ rowdata,
    float* __restrict__ out)
{
    const int t = blockIdx.x * 320 + threadIdx.x;
    float4 tb = ((const float4*)tboxes)[t];
    const int label = tlabels[t];
    const float tx0 = tb.x - 0.5f * tb.z, ty0 = tb.y - 0.5f * tb.w;
    const float tx1 = tb.x + 0.5f * tb.z, ty1 = tb.y + 0.5f * tb.w;
    const float tarea = (tx1 - tx0) * (ty1 - ty0);

    const int r0 = blockIdx.y * RPB;
    #pragma unroll 4
    for (int i = 0; i < RPB; ++i) {
        const int r = r0 + i;
        const float4* rd = (const float4*)(rowdata + (size_t)r * 12);
        const float4 pb  = rd[0];
        const float4 pxy = rd[1];
        const float4 ps  = rd[2];
        const float lg  = logits[(size_t)r * NC + label];
        const float cls = __expf(lg - ps.y) * ps.z;
        const float l1 = fabsf(pb.x - tb.x) + fabsf(pb.y - tb.y) +
                         fabsf(pb.z - tb.z) + fabsf(pb.w - tb.w);
        const float iw = fmaxf(fminf(pxy.z, tx1) - fmaxf(pxy.x, tx0), 0.0f);
        const float ih = fmaxf(fminf(pxy.w, ty1) - fmaxf(pxy.y, ty0), 0.0f);
        const float inter = iw * ih;
        const float uni   = ps.x + tarea - inter;
        const float iou   = inter * __builtin_amdgcn_rcpf(uni);
        const float ew = fmaxf(pxy.z, tx1) - fminf(pxy.x, tx0);
        const float eh = fmaxf(pxy.w, ty1) - fminf(pxy.y, ty0);
        const float earea = ew * eh;
        const float giou  = iou - (earea - uni) * __builtin_amdgcn_rcpf(earea);
        out[(size_t)r * NT + t] = 5.0f * l1 - cls - 2.0f * giou;
    }
}

extern "C" void kernel_launch(void* const* d_in, const int* in_sizes, int n_in,
                              void* d_out, int out_size, void* d_ws, size_t ws_size,
                              hipStream_t stream) {
    const float* logits  = (const float*)d_in[0];
    const float* pboxes  = (const float*)d_in[1];
    const int*   tlabels = (const int*)d_in[2];
    const float* tboxes  = (const float*)d_in[3];
    float* out = (float*)d_out;
    float* rowdata = (float*)d_ws;
    float* prob = (float*)((char*)d_ws + ROWDATA_BYTES);

    if (ws_size >= WS_NEEDED) {
        row_prep<<<dim3(NROWS / 4), 256, 0, stream>>>(logits, pboxes, rowdata, prob);
        cost_kernel<<<dim3(5, NROWS / RPB), 320, 0, stream>>>(
            tlabels, tboxes, rowdata, prob, out);
    } else {
        row_prep<<<dim3(NROWS / 4), 256, 0, stream>>>(logits, pboxes, rowdata, nullptr);
        cost_kernel_fb<<<dim3(5, NROWS / RPB), 320, 0, stream>>>(
            logits, tlabels, tboxes, rowdata, out);
    }
}